// Round 1
// baseline (9.779 us; speedup 1.0000x reference)
//
#include <hip/hip_runtime.h>
#include <hip/hip_bf16.h>

// labels[b,l,i] = argmin_j ( tn[b,l,i] - cbn[i,j] )  with tn constant over j
//               = argmax_j cbn[i,j] = argmax_j codebook[i,j]   (positive affine map)
// => output is the per-row argmax of the 64x64 codebook, broadcast over B*L.

#define C_DIM 64
#define Q_DIM 64

__global__ __launch_bounds__(256) void bestrq_labels_kernel(
    const float* __restrict__ codebook,  // (C=64, Q=64) f32
    int* __restrict__ out,               // (B*L, C) int32, flat
    int total4)                          // B*L*C / 4
{
    __shared__ int lab[C_DIM];  // 64 ints = 16 x int4

    const int t = threadIdx.x;
    if (t < C_DIM) {
        // Each of the first 64 threads scans one codebook row (64 floats, L1-hot).
        const float* row = codebook + t * Q_DIM;
        float best = row[0];
        int bj = 0;
#pragma unroll
        for (int j = 1; j < Q_DIM; ++j) {
            float v = row[j];
            if (v > best) { best = v; bj = j; }   // strict > keeps FIRST max == argmin tie-break
        }
        lab[t] = bj;
    }
    __syncthreads();

    const int4* lab4 = reinterpret_cast<const int4*>(lab);
    int4* o4 = reinterpret_cast<int4*>(out);
    // C=64 -> 16 int4 per output row; (p & 15) selects the column chunk.
    for (int p = blockIdx.x * blockDim.x + t; p < total4; p += gridDim.x * blockDim.x) {
        o4[p] = lab4[p & 15];
    }
}

extern "C" void kernel_launch(void* const* d_in, const int* in_sizes, int n_in,
                              void* d_out, int out_size, void* d_ws, size_t ws_size,
                              hipStream_t stream) {
    // inputs: d_in[0]=x (unused), d_in[1]=W (unused), d_in[2]=codebook (64*64 f32)
    const float* codebook = (const float*)d_in[2];
    int* out = (int*)d_out;

    const int total4 = out_size / 4;              // 1,048,576 / 4 = 262,144
    const int block = 256;
    int grid = (total4 + block - 1) / block;      // 1024
    if (grid > 2048) grid = 2048;

    bestrq_labels_kernel<<<grid, block, 0, stream>>>(codebook, out, total4);
}